// Round 4
// baseline (214.047 us; speedup 1.0000x reference)
//
#include <hip/hip_runtime.h>
#include <math.h>
#include <stdint.h>

// LayerSumSimple: K-level chained cummax-of-sums == max-plus affine scan with
// 8-element state s:  s[k] <- max(s[k], s[k-1] + g_k(t)),  g_k = x*w[k]+b[k].
//
// Round-10: SINGLE-KERNEL hierarchical decoupled lookback.
//  - 1024 blocks, ticket-ordered batch-major (b = ticket/128) so every
//    128-chunk chain is co-resident (capacity >= 128 guaranteed: LDS 64KB/block
//    -> 2 blocks/CU -> 512 resident; even 1/CU = 256 is safe). No deadlock.
//  - Each block: chunk summary (X stashed in LDS), publish map (agent scope);
//    group tails (c%8==7) compose 8 chunk maps -> group map; batch tail
//    (c==127) chains 16 group maps -> group inflows; all blocks replay <=7
//    sibling maps -> true inflow; rescan from LDS; NT-store outputs.
//  - X read from HBM ONCE. No pass2 launches, no inter-kernel gaps.
//  - Cross-XCD protocol: data via __hip_atomic_ agent-scope relaxed (coherent
//    at L3, bypasses per-XCD L2), s_waitcnt vmcnt(0) + __syncthreads() before
//    flag store; readers poll flag (agent) then load (control-dependent).
//  - Flags/ticket region zeroed by hipMemsetAsync each launch (workspace is
//    poisoned by the harness between iterations).
namespace {
constexpr int BB   = 8;
constexpr int TT   = 8192;
constexpr int DD   = 256;
constexpr int KK   = 8;
constexpr int TOUT = TT - KK + 1;       // 8185
constexpr int NSUM = 36;                // 8 c-vec + 28 strict-lower A
constexpr int C    = 128;               // chunks per sequence
constexpr int L    = TT / C;            // 64
constexpr int G    = 8;                 // chunks per group
constexpr int NG   = C / G;             // 16
constexpr int U    = 8;                 // pipeline batch (steps)
constexpr int NB   = L / U;             // 8
constexpr int MSTR = NSUM * DD;         // float stride between map regions

// flags region (uint32 indices into d_ws base); zeroed per launch
constexpr int FLG_TICKET = 0;
constexpr int FLG_C      = 16;                 // cflag[b*C+c]
constexpr int FLG_G      = FLG_C + BB * C;     // gflag[b*NG+g]
constexpr int FLG_I      = FLG_G + BB * NG;    // iflag[b*NG+g]
constexpr size_t FLAG_BYTES = 8192;

__host__ __device__ __forceinline__ constexpr int alin(int k, int j) {
    return k * (k - 1) / 2 + j;     // strict lower triangle, k in [1,8), j<k
}

// ---- agent-scope (cross-XCD coherent) memory ops ----
__device__ __forceinline__ float ldA(const float* p) {
    return __hip_atomic_load(p, __ATOMIC_RELAXED, __HIP_MEMORY_SCOPE_AGENT);
}
__device__ __forceinline__ void stA(float* p, float v) {
    __hip_atomic_store(p, v, __ATOMIC_RELAXED, __HIP_MEMORY_SCOPE_AGENT);
}
__device__ __forceinline__ uint32_t ldF(const uint32_t* p) {
    return __hip_atomic_load(p, __ATOMIC_RELAXED, __HIP_MEMORY_SCOPE_AGENT);
}
__device__ __forceinline__ void stF(uint32_t* p, uint32_t v) {
    __hip_atomic_store(p, v, __ATOMIC_RELAXED, __HIP_MEMORY_SCOPE_AGENT);
}
__device__ __forceinline__ void waitflag(const uint32_t* p) {
    while (ldF(p) == 0u) __builtin_amdgcn_s_sleep(2);
    asm volatile("" ::: "memory");  // keep data loads below the poll
}
// all own stores globally visible, then block-wide rendezvous
__device__ __forceinline__ void publish_fence() {
    asm volatile("s_waitcnt vmcnt(0)" ::: "memory");
    __syncthreads();
}

// one time-step of the summary recurrence (descending k uses OLD row k-1)
__device__ __forceinline__ void step_sum(float x, const float (&wk)[KK],
                                         const float (&bk)[KK],
                                         float (&a)[28], float (&cv)[KK])
{
    float g[KK];
    #pragma unroll
    for (int k = 0; k < KK; ++k) g[k] = fmaf(x, wk[k], bk[k]);
    #pragma unroll
    for (int k = KK - 1; k >= 2; --k) {
        #pragma unroll
        for (int j = 0; j < k - 1; ++j)
            a[alin(k, j)] = fmaxf(a[alin(k, j)], g[k] + a[alin(k - 1, j)]);
        a[alin(k, k - 1)] = fmaxf(a[alin(k, k - 1)], g[k]);
        cv[k] = fmaxf(cv[k], g[k] + cv[k - 1]);
    }
    a[alin(1, 0)] = fmaxf(a[alin(1, 0)], g[1]);
    cv[1] = fmaxf(cv[1], g[1] + cv[0]);
    cv[0] = fmaxf(cv[0], g[0]);
}

__device__ __forceinline__ void step_scan(float x, const float (&wk)[KK],
                                          const float (&bk)[KK], float (&s)[KK])
{
    float g[KK];
    #pragma unroll
    for (int k = 0; k < KK; ++k) g[k] = fmaf(x, wk[k], bk[k]);
    #pragma unroll
    for (int k = KK - 1; k >= 1; --k) s[k] = fmaxf(s[k], s[k - 1] + g[k]);
    s[0] = fmaxf(s[0], g[0]);
}

// agent-scope plane-layout map load (36 coalesced dword loads)
__device__ __forceinline__ void ld_mapA(const float* __restrict__ p,
                                        float (&mc)[KK], float (&ma)[28])
{
    #pragma unroll
    for (int i = 0; i < KK; ++i) mc[i] = ldA(p + i * DD);
    #pragma unroll
    for (int i = 0; i < 28; ++i) ma[i] = ldA(p + (8 + i) * DD);
}

// s <- apply(map (mc,ma), s)
__device__ __forceinline__ void apply2(const float (&mc)[KK], const float (&ma)[28],
                                       float (&s)[KK])
{
    float ns[KK];
    #pragma unroll
    for (int k = 0; k < KK; ++k) ns[k] = fmaxf(mc[k], s[k]);
    #pragma unroll
    for (int k = 1; k < KK; ++k) {
        #pragma unroll
        for (int j = 0; j < k; ++j) ns[k] = fmaxf(ns[k], ma[alin(k, j)] + s[j]);
    }
    #pragma unroll
    for (int k = 0; k < KK; ++k) s[k] = ns[k];
}

// (R,cv) <- compose(map (mc,ma) AFTER accumulated (R,cv))
__device__ __forceinline__ void compose2(const float (&mc)[KK], const float (&ma)[28],
                                         float (&R)[28], float (&cv)[KK])
{
    float nc[KK];
    #pragma unroll
    for (int i = 0; i < KK; ++i) {
        float v = fmaxf(mc[i], cv[i]);
        #pragma unroll
        for (int j = 0; j < i; ++j) v = fmaxf(v, ma[alin(i, j)] + cv[j]);
        nc[i] = v;
    }
    float nR[28];
    #pragma unroll
    for (int i = 1; i < KK; ++i) {
        #pragma unroll
        for (int j = 0; j < i; ++j) {
            float v = fmaxf(R[alin(i, j)], ma[alin(i, j)]);
            #pragma unroll
            for (int mm = j + 1; mm < i; ++mm)
                v = fmaxf(v, ma[alin(i, mm)] + R[alin(mm, j)]);
            nR[alin(i, j)] = v;
        }
    }
    #pragma unroll
    for (int i = 0; i < KK; ++i) cv[i] = nc[i];
    #pragma unroll
    for (int i = 0; i < 28; ++i) R[i] = nR[i];
}

__global__ __launch_bounds__(256) void fused_scan(
    const float* __restrict__ X, const float* __restrict__ W,
    const float* __restrict__ Bv, uint32_t* __restrict__ flg,
    float* __restrict__ sum, float* __restrict__ gm,
    float* __restrict__ ginfl, float* __restrict__ out)
{
    __shared__ float xs[L * DD];          // 64 KB X stash
    __shared__ uint32_t tkt_s;
    const int d = threadIdx.x;

    if (d == 0) tkt_s = atomicAdd(flg + FLG_TICKET, 1u);
    __syncthreads();
    const int T = (int)tkt_s;
    const int b = T / C;                  // batch-major tickets: whole chain
    const int c = T % C;                  // co-resident -> deadlock-free
    const int g = c / G;
    const int p = c % G;

    float wk[KK], bk[KK];
    #pragma unroll
    for (int k = 0; k < KK; ++k) { wk[k] = W[k * DD + d]; bk[k] = Bv[k * DD + d]; }

    // ---- phase 1: chunk summary, stashing X rows in LDS ----
    float cva[KK], aa[28];
    #pragma unroll
    for (int k = 0; k < KK; ++k) cva[k] = -INFINITY;
    #pragma unroll
    for (int i = 0; i < 28; ++i) aa[i] = -INFINITY;

    const float* xp = X + ((size_t)(b * TT + c * L)) * DD + d;
    float x0[U], x1[U];
    #pragma unroll
    for (int u = 0; u < U; ++u) x0[u] = xp[u * DD];

    int tw = 0;
    #pragma unroll 1
    for (int ib = 0; ib + 2 < NB; ib += 2) {
        #pragma unroll
        for (int u = 0; u < U; ++u) x1[u] = xp[(U + u) * DD];
        #pragma unroll
        for (int u = 0; u < U; ++u) { xs[(tw + u) * DD + d] = x0[u]; step_sum(x0[u], wk, bk, aa, cva); }
        tw += U;
        #pragma unroll
        for (int u = 0; u < U; ++u) x0[u] = xp[(2 * U + u) * DD];
        #pragma unroll
        for (int u = 0; u < U; ++u) { xs[(tw + u) * DD + d] = x1[u]; step_sum(x1[u], wk, bk, aa, cva); }
        tw += U;
        xp += 2 * U * DD;
    }
    #pragma unroll
    for (int u = 0; u < U; ++u) x1[u] = xp[(U + u) * DD];
    #pragma unroll
    for (int u = 0; u < U; ++u) { xs[(tw + u) * DD + d] = x0[u]; step_sum(x0[u], wk, bk, aa, cva); }
    tw += U;
    #pragma unroll
    for (int u = 0; u < U; ++u) { xs[(tw + u) * DD + d] = x1[u]; step_sum(x1[u], wk, bk, aa, cva); }

    // ---- phase 2: publish / hierarchy ----
    float s[KK];
    #pragma unroll
    for (int k = 0; k < KK; ++k) s[k] = -INFINITY;

    const float* gbase = sum + ((size_t)(b * C + g * G)) * MSTR + d;  // group's chunk maps

    if (p != G - 1) {
        // regular chunk: publish own map (read by group tail + sibling replays)
        float* sp = sum + ((size_t)(b * C + c)) * MSTR + d;
        #pragma unroll
        for (int k = 0; k < KK; ++k) stA(sp + k * DD, cva[k]);
        #pragma unroll
        for (int i = 0; i < 28; ++i) stA(sp + (8 + i) * DD, aa[i]);
        publish_fence();
        if (d == 0) stF(flg + FLG_C + b * C + c, 1u);
    } else {
        // group tail: compose 8 chunk maps -> group map
        float R[28], cv[KK], mc[KK], ma[28];
        waitflag(flg + FLG_C + b * C + g * G);
        ld_mapA(gbase, mc, ma);
        #pragma unroll
        for (int i = 0; i < 28; ++i) R[i] = ma[i];
        #pragma unroll
        for (int i = 0; i < KK; ++i) cv[i] = mc[i];
        #pragma unroll 1
        for (int j = 1; j < G - 1; ++j) {
            waitflag(flg + FLG_C + b * C + g * G + j);
            ld_mapA(gbase + (size_t)j * MSTR, mc, ma);
            compose2(mc, ma, R, cv);
        }
        compose2(cva, aa, R, cv);          // own (last) map from registers

        float* gp = gm + ((size_t)(b * NG + g)) * MSTR + d;
        #pragma unroll
        for (int i = 0; i < KK; ++i) stA(gp + i * DD, cv[i]);
        #pragma unroll
        for (int i = 0; i < 28; ++i) stA(gp + (8 + i) * DD, R[i]);
        publish_fence();
        if (d == 0) stF(flg + FLG_G + b * NG + g, 1u);

        if (c == C - 1) {
            // batch tail: serial chain over 16 group maps -> group inflows
            float* ip = ginfl + ((size_t)(b * NG)) * KK * DD + d;
            #pragma unroll 1
            for (int g2 = 0; g2 < NG; ++g2) {
                #pragma unroll
                for (int k = 0; k < KK; ++k) stA(ip + (size_t)(g2 * KK + k) * DD, s[k]);
                publish_fence();
                if (d == 0) stF(flg + FLG_I + b * NG + g2, 1u);
                if (g2 < NG - 1) {
                    waitflag(flg + FLG_G + b * NG + g2);
                    ld_mapA(gm + ((size_t)(b * NG + g2)) * MSTR + d, mc, ma);
                    apply2(mc, ma, s);
                }
            }
            // s now = inflow(group NG-1); replay own 7 siblings (flags already seen)
            #pragma unroll 1
            for (int j = 0; j < G - 1; ++j) {
                ld_mapA(gbase + (size_t)j * MSTR, mc, ma);
                apply2(mc, ma, s);
            }
        }
    }

    // ---- phase 3a: resolve inflow (all blocks except batch tail) ----
    if (c != C - 1) {
        if (g > 0) {
            waitflag(flg + FLG_I + b * NG + g);
            const float* ip = ginfl + ((size_t)(b * NG + g)) * KK * DD + d;
            #pragma unroll
            for (int k = 0; k < KK; ++k) s[k] = ldA(ip + k * DD);
        }
        float mc[KK], ma[28];
        #pragma unroll 1
        for (int j = 0; j < p; ++j) {
            waitflag(flg + FLG_C + b * C + g * G + j);
            ld_mapA(gbase + (size_t)j * MSTR, mc, ma);
            apply2(mc, ma, s);
        }
    }

    // ---- phase 3b: rescan from LDS stash, emit outputs ----
    const int t0c = c * L;
    float* op = out + (size_t)b * TOUT * DD + (ptrdiff_t)(t0c - (KK - 1)) * DD + d;
    #pragma unroll 1
    for (int tb = 0; tb < NB; ++tb) {
        float xv[U];
        #pragma unroll
        for (int u = 0; u < U; ++u) xv[u] = xs[(tb * U + u) * DD + d];
        #pragma unroll
        for (int u = 0; u < U; ++u) {
            const int t = tb * U + u;
            step_scan(xv[u], wk, bk, s);
            if (t0c + t >= KK - 1)
                __builtin_nontemporal_store(s[KK - 1], &op[t * DD]);
        }
    }
}
} // namespace

extern "C" void kernel_launch(void* const* d_in, const int* in_sizes, int n_in,
                              void* d_out, int out_size, void* d_ws, size_t ws_size,
                              hipStream_t stream)
{
    const float* X  = (const float*)d_in[0];
    const float* W  = (const float*)d_in[1];
    const float* Bv = (const float*)d_in[2];
    float* out = (float*)d_out;

    uint32_t* flg = (uint32_t*)d_ws;
    float* fbase  = (float*)((char*)d_ws + FLAG_BYTES);
    float* sum    = fbase;                                   // 37.75 MB
    float* gmp    = sum + (size_t)BB * C  * MSTR;            //  4.72 MB
    float* ginfl  = gmp + (size_t)BB * NG * MSTR;            //  1.05 MB

    hipMemsetAsync(d_ws, 0, FLAG_BYTES, stream);   // zero ticket + flags
    fused_scan<<<BB * C, 256, 0, stream>>>(X, W, Bv, flg, sum, gmp, ginfl, out);
}

// Round 5
// 200.120 us; speedup vs baseline: 1.0696x; 1.0696x over previous
//
#include <hip/hip_runtime.h>
#include <math.h>
#include <stdint.h>

// LayerSumSimple: K-level chained cummax-of-sums == max-plus affine scan with
// 8-element state s:  s[k] <- max(s[k], s[k-1] + g_k(t)),  g_k = x*w[k]+b[k].
//
// Round-11: fused single-kernel v2 (protocol verified correct in round-10).
//  Changes vs v1, both aimed at the measured Occupancy=17% / VALUBusy=34%:
//   - NO LDS X-stash (LDS=0): residency 2 -> ~5 blocks/CU; X re-read in the
//     rescan phase instead (HBM was at 17% util - bandwidth is free).
//   - batch-tail serial group chain REPLACED by per-group-tail parallel
//     lookback (each tail composes already-published group maps itself);
//     removes ~16 publish-fence round-trips from the critical path.
//   - phase-3b X prefetch issued BEFORE the inflow spin (latency hides there);
//     NT out stores keep X + maps L3-resident.
//  Ticket ordering (batch-major) retained: any residency >=128 blocks is
//  deadlock-free; actual residency is the full 1024.
namespace {
constexpr int BB   = 8;
constexpr int TT   = 8192;
constexpr int DD   = 256;
constexpr int KK   = 8;
constexpr int TOUT = TT - KK + 1;       // 8185
constexpr int NSUM = 36;                // 8 c-vec + 28 strict-lower A
constexpr int C    = 128;               // chunks per sequence
constexpr int L    = TT / C;            // 64
constexpr int G    = 8;                 // chunks per group
constexpr int NG   = C / G;             // 16
constexpr int U    = 8;                 // phase-1 pipeline batch
constexpr int NB   = L / U;             // 8
constexpr int MSTR = NSUM * DD;         // float stride between map regions

// flags region (uint32 indices into d_ws base); zeroed per launch
constexpr int FLG_TICKET = 0;
constexpr int FLG_C      = 16;                 // cflag[b*C+c]
constexpr int FLG_G      = FLG_C + BB * C;     // gflag[b*NG+g]
constexpr int FLG_I      = FLG_G + BB * NG;    // iflag[b*NG+g]
constexpr size_t FLAG_BYTES = 8192;

__host__ __device__ __forceinline__ constexpr int alin(int k, int j) {
    return k * (k - 1) / 2 + j;     // strict lower triangle, k in [1,8), j<k
}

// ---- agent-scope (cross-XCD coherent) memory ops ----
__device__ __forceinline__ float ldA(const float* p) {
    return __hip_atomic_load(p, __ATOMIC_RELAXED, __HIP_MEMORY_SCOPE_AGENT);
}
__device__ __forceinline__ void stA(float* p, float v) {
    __hip_atomic_store(p, v, __ATOMIC_RELAXED, __HIP_MEMORY_SCOPE_AGENT);
}
__device__ __forceinline__ uint32_t ldF(const uint32_t* p) {
    return __hip_atomic_load(p, __ATOMIC_RELAXED, __HIP_MEMORY_SCOPE_AGENT);
}
__device__ __forceinline__ void stF(uint32_t* p, uint32_t v) {
    __hip_atomic_store(p, v, __ATOMIC_RELAXED, __HIP_MEMORY_SCOPE_AGENT);
}
__device__ __forceinline__ void waitflag(const uint32_t* p) {
    while (ldF(p) == 0u) __builtin_amdgcn_s_sleep(2);
    asm volatile("" ::: "memory");  // keep data loads below the poll
}
// all own stores globally visible, then block-wide rendezvous
__device__ __forceinline__ void publish_fence() {
    asm volatile("s_waitcnt vmcnt(0)" ::: "memory");
    __syncthreads();
}

// one time-step of the summary recurrence (descending k uses OLD row k-1)
__device__ __forceinline__ void step_sum(float x, const float (&wk)[KK],
                                         const float (&bk)[KK],
                                         float (&a)[28], float (&cv)[KK])
{
    float g[KK];
    #pragma unroll
    for (int k = 0; k < KK; ++k) g[k] = fmaf(x, wk[k], bk[k]);
    #pragma unroll
    for (int k = KK - 1; k >= 2; --k) {
        #pragma unroll
        for (int j = 0; j < k - 1; ++j)
            a[alin(k, j)] = fmaxf(a[alin(k, j)], g[k] + a[alin(k - 1, j)]);
        a[alin(k, k - 1)] = fmaxf(a[alin(k, k - 1)], g[k]);
        cv[k] = fmaxf(cv[k], g[k] + cv[k - 1]);
    }
    a[alin(1, 0)] = fmaxf(a[alin(1, 0)], g[1]);
    cv[1] = fmaxf(cv[1], g[1] + cv[0]);
    cv[0] = fmaxf(cv[0], g[0]);
}

__device__ __forceinline__ void step_scan(float x, const float (&wk)[KK],
                                          const float (&bk)[KK], float (&s)[KK])
{
    float g[KK];
    #pragma unroll
    for (int k = 0; k < KK; ++k) g[k] = fmaf(x, wk[k], bk[k]);
    #pragma unroll
    for (int k = KK - 1; k >= 1; --k) s[k] = fmaxf(s[k], s[k - 1] + g[k]);
    s[0] = fmaxf(s[0], g[0]);
}

// agent-scope plane-layout map load (36 coalesced dword loads)
__device__ __forceinline__ void ld_mapA(const float* __restrict__ p,
                                        float (&mc)[KK], float (&ma)[28])
{
    #pragma unroll
    for (int i = 0; i < KK; ++i) mc[i] = ldA(p + i * DD);
    #pragma unroll
    for (int i = 0; i < 28; ++i) ma[i] = ldA(p + (8 + i) * DD);
}

// s <- apply(map (mc,ma), s)
__device__ __forceinline__ void apply2(const float (&mc)[KK], const float (&ma)[28],
                                       float (&s)[KK])
{
    float ns[KK];
    #pragma unroll
    for (int k = 0; k < KK; ++k) ns[k] = fmaxf(mc[k], s[k]);
    #pragma unroll
    for (int k = 1; k < KK; ++k) {
        #pragma unroll
        for (int j = 0; j < k; ++j) ns[k] = fmaxf(ns[k], ma[alin(k, j)] + s[j]);
    }
    #pragma unroll
    for (int k = 0; k < KK; ++k) s[k] = ns[k];
}

// (R,cv) <- compose(map (mc,ma) AFTER accumulated (R,cv))
__device__ __forceinline__ void compose2(const float (&mc)[KK], const float (&ma)[28],
                                         float (&R)[28], float (&cv)[KK])
{
    float nc[KK];
    #pragma unroll
    for (int i = 0; i < KK; ++i) {
        float v = fmaxf(mc[i], cv[i]);
        #pragma unroll
        for (int j = 0; j < i; ++j) v = fmaxf(v, ma[alin(i, j)] + cv[j]);
        nc[i] = v;
    }
    float nR[28];
    #pragma unroll
    for (int i = 1; i < KK; ++i) {
        #pragma unroll
        for (int j = 0; j < i; ++j) {
            float v = fmaxf(R[alin(i, j)], ma[alin(i, j)]);
            #pragma unroll
            for (int mm = j + 1; mm < i; ++mm)
                v = fmaxf(v, ma[alin(i, mm)] + R[alin(mm, j)]);
            nR[alin(i, j)] = v;
        }
    }
    #pragma unroll
    for (int i = 0; i < KK; ++i) cv[i] = nc[i];
    #pragma unroll
    for (int i = 0; i < 28; ++i) R[i] = nR[i];
}

__global__ __launch_bounds__(256) void fused_scan(
    const float* __restrict__ X, const float* __restrict__ W,
    const float* __restrict__ Bv, uint32_t* __restrict__ flg,
    float* __restrict__ sum, float* __restrict__ gm,
    float* __restrict__ ginfl, float* __restrict__ out)
{
    __shared__ uint32_t tkt_s;
    const int d = threadIdx.x;

    if (d == 0) tkt_s = atomicAdd(flg + FLG_TICKET, 1u);
    __syncthreads();
    const int T = (int)tkt_s;
    const int b = T / C;                  // batch-major tickets: whole chain
    const int c = T % C;                  // co-resident -> deadlock-free
    const int g = c / G;
    const int p = c % G;

    float wk[KK], bk[KK];
    #pragma unroll
    for (int k = 0; k < KK; ++k) { wk[k] = W[k * DD + d]; bk[k] = Bv[k * DD + d]; }

    // ---- phase 1: chunk summary (no LDS stash; X re-read in phase 3b) ----
    float cva[KK], aa[28];
    #pragma unroll
    for (int k = 0; k < KK; ++k) cva[k] = -INFINITY;
    #pragma unroll
    for (int i = 0; i < 28; ++i) aa[i] = -INFINITY;

    {
        const float* xp = X + ((size_t)(b * TT + c * L)) * DD + d;
        float x0[U], x1[U];
        #pragma unroll
        for (int u = 0; u < U; ++u) x0[u] = xp[u * DD];
        #pragma unroll 1
        for (int ib = 0; ib + 2 < NB; ib += 2) {
            #pragma unroll
            for (int u = 0; u < U; ++u) x1[u] = xp[(U + u) * DD];
            #pragma unroll
            for (int u = 0; u < U; ++u) step_sum(x0[u], wk, bk, aa, cva);
            #pragma unroll
            for (int u = 0; u < U; ++u) x0[u] = xp[(2 * U + u) * DD];
            #pragma unroll
            for (int u = 0; u < U; ++u) step_sum(x1[u], wk, bk, aa, cva);
            xp += 2 * U * DD;
        }
        #pragma unroll
        for (int u = 0; u < U; ++u) x1[u] = xp[(U + u) * DD];
        #pragma unroll
        for (int u = 0; u < U; ++u) step_sum(x0[u], wk, bk, aa, cva);
        #pragma unroll
        for (int u = 0; u < U; ++u) step_sum(x1[u], wk, bk, aa, cva);
    }

    // ---- phase 2 + 3a: publish / hierarchy / inflow resolution ----
    float s[KK];
    #pragma unroll
    for (int k = 0; k < KK; ++k) s[k] = -INFINITY;

    const float* gbase = sum + ((size_t)(b * C + g * G)) * MSTR + d;
    const float* xq    = X + ((size_t)(b * TT + c * L)) * DD + d;
    float x0[16];                          // phase-3b prefetch (16 rows)

    if (p != G - 1) {
        // regular chunk: publish own map, prefetch X, wait inflow, replay sibs
        float* sp = sum + ((size_t)(b * C + c)) * MSTR + d;
        #pragma unroll
        for (int k = 0; k < KK; ++k) stA(sp + k * DD, cva[k]);
        #pragma unroll
        for (int i = 0; i < 28; ++i) stA(sp + (8 + i) * DD, aa[i]);
        publish_fence();
        if (d == 0) stF(flg + FLG_C + b * C + c, 1u);

        #pragma unroll
        for (int u = 0; u < 16; ++u) x0[u] = xq[u * DD];   // hide under spins

        if (g > 0) {
            waitflag(flg + FLG_I + b * NG + g);
            const float* ip = ginfl + ((size_t)(b * NG + g)) * KK * DD + d;
            #pragma unroll
            for (int k = 0; k < KK; ++k) s[k] = ldA(ip + k * DD);
        }
        float mc[KK], ma[28];
        #pragma unroll 1
        for (int j = 0; j < p; ++j) {
            waitflag(flg + FLG_C + b * C + g * G + j);
            ld_mapA(gbase + (size_t)j * MSTR, mc, ma);
            apply2(mc, ma, s);
        }
    } else {
        // group tail: compose 8 chunk maps -> group map
        float R[28], cv[KK], mc[KK], ma[28];
        waitflag(flg + FLG_C + b * C + g * G);
        ld_mapA(gbase, mc, ma);
        #pragma unroll
        for (int i = 0; i < 28; ++i) R[i] = ma[i];
        #pragma unroll
        for (int i = 0; i < KK; ++i) cv[i] = mc[i];
        #pragma unroll 1
        for (int j = 1; j < G - 1; ++j) {
            waitflag(flg + FLG_C + b * C + g * G + j);
            ld_mapA(gbase + (size_t)j * MSTR, mc, ma);
            compose2(mc, ma, R, cv);
        }
        compose2(cva, aa, R, cv);          // own (last) map from registers

        float* gp = gm + ((size_t)(b * NG + g)) * MSTR + d;
        #pragma unroll
        for (int i = 0; i < KK; ++i) stA(gp + i * DD, cv[i]);
        #pragma unroll
        for (int i = 0; i < 28; ++i) stA(gp + (8 + i) * DD, R[i]);
        publish_fence();
        if (d == 0) stF(flg + FLG_G + b * NG + g, 1u);

        #pragma unroll
        for (int u = 0; u < 16; ++u) x0[u] = xq[u * DD];   // hide under lookback

        // parallel lookback: group inflow = gmap[g-1] o ... o gmap[0] (-inf)
        #pragma unroll 1
        for (int j = 0; j < g; ++j) {
            waitflag(flg + FLG_G + b * NG + j);
            ld_mapA(gm + ((size_t)(b * NG + j)) * MSTR + d, mc, ma);
            apply2(mc, ma, s);
        }
        float* ip = ginfl + ((size_t)(b * NG + g)) * KK * DD + d;
        #pragma unroll
        for (int k = 0; k < KK; ++k) stA(ip + k * DD, s[k]);
        publish_fence();
        if (d == 0) stF(flg + FLG_I + b * NG + g, 1u);

        // own chunk inflow: replay 7 siblings (cflags already observed)
        #pragma unroll 1
        for (int j = 0; j < G - 1; ++j) {
            ld_mapA(gbase + (size_t)j * MSTR, mc, ma);
            apply2(mc, ma, s);
        }
    }

    // ---- phase 3b: rescan from global X (prefetched), NT-store outputs ----
    const int t0c = c * L;
    float* op = out + (size_t)b * TOUT * DD + (ptrdiff_t)(t0c - (KK - 1)) * DD + d;
    float x1[16];
    int t = 0;
    #pragma unroll 1
    for (int ib = 0; ib + 2 < 4; ib += 2) {        // L/16 = 4 batches
        #pragma unroll
        for (int u = 0; u < 16; ++u) x1[u] = xq[(16 + u) * DD];
        #pragma unroll
        for (int u = 0; u < 16; ++u) {
            step_scan(x0[u], wk, bk, s);
            if (t0c + t >= KK - 1) __builtin_nontemporal_store(s[KK - 1], &op[t * DD]);
            ++t;
        }
        #pragma unroll
        for (int u = 0; u < 16; ++u) x0[u] = xq[(32 + u) * DD];
        #pragma unroll
        for (int u = 0; u < 16; ++u) {
            step_scan(x1[u], wk, bk, s);
            if (t0c + t >= KK - 1) __builtin_nontemporal_store(s[KK - 1], &op[t * DD]);
            ++t;
        }
        xq += 32 * DD;
    }
    #pragma unroll
    for (int u = 0; u < 16; ++u) x1[u] = xq[(16 + u) * DD];
    #pragma unroll
    for (int u = 0; u < 16; ++u) {
        step_scan(x0[u], wk, bk, s);
        if (t0c + t >= KK - 1) __builtin_nontemporal_store(s[KK - 1], &op[t * DD]);
        ++t;
    }
    #pragma unroll
    for (int u = 0; u < 16; ++u) {
        step_scan(x1[u], wk, bk, s);
        if (t0c + t >= KK - 1) __builtin_nontemporal_store(s[KK - 1], &op[t * DD]);
        ++t;
    }
}
} // namespace

extern "C" void kernel_launch(void* const* d_in, const int* in_sizes, int n_in,
                              void* d_out, int out_size, void* d_ws, size_t ws_size,
                              hipStream_t stream)
{
    const float* X  = (const float*)d_in[0];
    const float* W  = (const float*)d_in[1];
    const float* Bv = (const float*)d_in[2];
    float* out = (float*)d_out;

    uint32_t* flg = (uint32_t*)d_ws;
    float* fbase  = (float*)((char*)d_ws + FLAG_BYTES);
    float* sum    = fbase;                                   // 37.75 MB
    float* gmp    = sum + (size_t)BB * C  * MSTR;            //  4.72 MB
    float* ginfl  = gmp + (size_t)BB * NG * MSTR;            //  1.05 MB

    hipMemsetAsync(d_ws, 0, FLAG_BYTES, stream);   // zero ticket + flags
    fused_scan<<<BB * C, 256, 0, stream>>>(X, W, Bv, flg, sum, gmp, ginfl, out);
}

// Round 6
// 186.330 us; speedup vs baseline: 1.1488x; 1.0740x over previous
//
#include <hip/hip_runtime.h>
#include <math.h>

// LayerSumSimple: K-level chained cummax-of-sums == max-plus affine scan with
// 8-element state s:  s[k] <- max(s[k], s[k-1] + g_k(t)),  g_k = x*w[k]+b[k].
// Round-12: round-3's verified 5-pass skeleton, C=128 -> 256 (L=32).
//  Rationale (accounting across r1-r5: total = ~83us harness fills + kernels):
//  pass1/pass3 at C=128 run 1024 blocks = 4 waves/SIMD (50% occupancy cap) and
//  sit 1.7-2x above their issue/BW floors. C=256 -> 2048 blocks doubles
//  resident waves (VGPR-capped ~5-7/SIMD), doubling latency hiding for both
//  the VALU-bound map build (pass1) and the BW-bound rescan (pass3), at the
//  cost of 2x map volume (75.5 MB) read by pass2a/2c (+~5us). Hierarchy:
//  G=16 chunks/group, NG=16 groups. Fused single-kernel line abandoned:
//  117us kernel vs 86us multi-pass, unexplained spin-cascade latency tail.
// All workspace arrays use PLANE layout: plane i of region r at
// base[r*NPLANES*DD + i*DD + d] -> lane d accesses are fully coalesced.
namespace {
constexpr int BB   = 8;
constexpr int TT   = 8192;
constexpr int DD   = 256;
constexpr int KK   = 8;
constexpr int TOUT = TT - KK + 1;       // 8185
constexpr int NSUM = 36;                // 8 c-vec + 28 strict-lower A
constexpr int C    = 256;               // chunks per sequence (was 128)
constexpr int L    = TT / C;            // 32
constexpr int G    = 16;                // chunks per group
constexpr int NG   = C / G;             // 16
constexpr int MSTR = NSUM * DD;         // float stride between map regions

// strict-lower-triangle linear index: k in [1,8), j < k  ->  [0,28)
__host__ __device__ __forceinline__ constexpr int alin(int k, int j) {
    return k * (k - 1) / 2 + j;
}
// plane index of A[k][j] in the 36-plane map layout (planes 0..7 = c-vec)
__host__ __device__ __forceinline__ constexpr int tri(int k, int j) {
    return 8 + alin(k, j);
}

// one time-step of the summary recurrence (descending k uses OLD row k-1).
__device__ __forceinline__ void step_sum(float x, const float (&wk)[KK],
                                         const float (&bk)[KK],
                                         float (&a)[28], float (&cv)[KK])
{
    float g[KK];
    #pragma unroll
    for (int k = 0; k < KK; ++k) g[k] = fmaf(x, wk[k], bk[k]);
    #pragma unroll
    for (int k = KK - 1; k >= 2; --k) {
        #pragma unroll
        for (int j = 0; j < k - 1; ++j)
            a[alin(k, j)] = fmaxf(a[alin(k, j)], g[k] + a[alin(k - 1, j)]);
        a[alin(k, k - 1)] = fmaxf(a[alin(k, k - 1)], g[k]);  // diag of row k-1 == 0
        cv[k] = fmaxf(cv[k], g[k] + cv[k - 1]);              // OLD cv[k-1]
    }
    a[alin(1, 0)] = fmaxf(a[alin(1, 0)], g[1]);
    cv[1] = fmaxf(cv[1], g[1] + cv[0]);
    cv[0] = fmaxf(cv[0], g[0]);
}

// ---- pass 1: one block per (b, chunk); thread d = channel ----
__global__ __launch_bounds__(256) void pass1_summaries(
    const float* __restrict__ X, const float* __restrict__ W,
    const float* __restrict__ Bv, float* __restrict__ sum)
{
    constexpr int U  = 8;
    constexpr int NB = L / U;           // 4
    const int b = blockIdx.x / C;
    const int c = blockIdx.x % C;
    const int d = threadIdx.x;

    float wk[KK], bk[KK];
    #pragma unroll
    for (int k = 0; k < KK; ++k) { wk[k] = W[k * DD + d]; bk[k] = Bv[k * DD + d]; }

    float cv[KK];
    float a[28];
    #pragma unroll
    for (int k = 0; k < KK; ++k) cv[k] = -INFINITY;
    #pragma unroll
    for (int i = 0; i < 28; ++i) a[i] = -INFINITY;

    const float* xp = X + ((size_t)(b * TT + c * L)) * DD + d;
    float x0[U], x1[U];
    #pragma unroll
    for (int u = 0; u < U; ++u) x0[u] = xp[u * DD];

    #pragma unroll 1
    for (int ib = 0; ib + 2 < NB; ib += 2) {
        #pragma unroll
        for (int u = 0; u < U; ++u) x1[u] = xp[(U + u) * DD];
        #pragma unroll
        for (int u = 0; u < U; ++u) step_sum(x0[u], wk, bk, a, cv);
        #pragma unroll
        for (int u = 0; u < U; ++u) x0[u] = xp[(2 * U + u) * DD];
        #pragma unroll
        for (int u = 0; u < U; ++u) step_sum(x1[u], wk, bk, a, cv);
        xp += 2 * U * DD;
    }
    // tail: batches NB-2 (in x0) and NB-1
    #pragma unroll
    for (int u = 0; u < U; ++u) x1[u] = xp[(U + u) * DD];
    #pragma unroll
    for (int u = 0; u < U; ++u) step_sum(x0[u], wk, bk, a, cv);
    #pragma unroll
    for (int u = 0; u < U; ++u) step_sum(x1[u], wk, bk, a, cv);

    // plane-layout store: 36 coalesced 1KB stores
    float* sp = sum + (size_t)blockIdx.x * MSTR + d;   // region = b*C + c
    #pragma unroll
    for (int k = 0; k < KK; ++k) sp[k * DD] = cv[k];
    #pragma unroll
    for (int i = 0; i < 28; ++i) sp[(8 + i) * DD] = a[i];
}

// plane-layout map load: 36 coalesced scalar loads into registers
__device__ __forceinline__ void ld_map(const float* __restrict__ p,
                                       float (&m)[NSUM])
{
    #pragma unroll
    for (int i = 0; i < NSUM; ++i) m[i] = p[i * DD];
}

// s <- apply(map m, s)
__device__ __forceinline__ void apply_map(const float (&m)[NSUM], float (&s)[KK])
{
    float ns[KK];
    #pragma unroll
    for (int k = 0; k < KK; ++k) ns[k] = fmaxf(m[k], s[k]);   // c[k], diag
    #pragma unroll
    for (int k = 1; k < KK; ++k) {
        #pragma unroll
        for (int j = 0; j < k; ++j) ns[k] = fmaxf(ns[k], m[tri(k, j)] + s[j]);
    }
    #pragma unroll
    for (int k = 0; k < KK; ++k) s[k] = ns[k];
}

// (R,cv) <- compose(map m, (R,cv))   [m applied AFTER accumulated (R,cv)]
__device__ __forceinline__ void compose_map(const float (&m)[NSUM],
                                            float (&R)[KK][KK], float (&cv)[KK])
{
    float nc[KK];
    #pragma unroll
    for (int i = 0; i < KK; ++i) {
        float v = fmaxf(m[i], cv[i]);
        #pragma unroll
        for (int j = 0; j < i; ++j) v = fmaxf(v, m[tri(i, j)] + cv[j]);
        nc[i] = v;
    }
    float nR[KK][KK];
    #pragma unroll
    for (int i = 1; i < KK; ++i) {
        #pragma unroll
        for (int j = 0; j < i; ++j) {
            float v = fmaxf(R[i][j], m[tri(i, j)]);
            #pragma unroll
            for (int mm = j + 1; mm < i; ++mm)
                v = fmaxf(v, m[tri(i, mm)] + R[mm][j]);
            nR[i][j] = v;
        }
    }
    #pragma unroll
    for (int i = 0; i < KK; ++i) {
        cv[i] = nc[i];
        #pragma unroll
        for (int j = 0; j < i; ++j) R[i][j] = nR[i][j];
    }
}

// ---- pass 2a: one block per (b, group); compose G=16 chunk maps ----
__global__ __launch_bounds__(256) void pass2a_groups(
    const float* __restrict__ sum, float* __restrict__ gsum)
{
    const int b = blockIdx.x / NG;
    const int g = blockIdx.x % NG;
    const int d = threadIdx.x;

    float R[KK][KK], cv[KK];
    #pragma unroll
    for (int i = 0; i < KK; ++i) {
        cv[i] = -INFINITY;
        #pragma unroll
        for (int j = 0; j < KK; ++j) R[i][j] = -INFINITY;
    }

    const float* mp = sum + ((size_t)(b * C + g * G)) * MSTR + d;
    float m0[NSUM], m1[NSUM];
    ld_map(mp, m0);
    #pragma unroll 1
    for (int ci = 0; ci + 2 < G; ci += 2) {
        ld_map(mp + MSTR, m1);
        compose_map(m0, R, cv);
        ld_map(mp + 2 * MSTR, m0);
        compose_map(m1, R, cv);
        mp += 2 * MSTR;
    }
    ld_map(mp + MSTR, m1);
    compose_map(m0, R, cv);
    compose_map(m1, R, cv);

    float* gp = gsum + (size_t)blockIdx.x * MSTR + d;  // region = b*NG + g
    #pragma unroll
    for (int i = 0; i < KK; ++i) gp[i * DD] = cv[i];
    #pragma unroll
    for (int i = 1; i < KK; ++i) {
        #pragma unroll
        for (int j = 0; j < i; ++j) gp[tri(i, j) * DD] = R[i][j];
    }
}

// ---- pass 2b: one block per b; serial apply over NG=16 group maps ----
__global__ __launch_bounds__(256) void pass2b_scan_groups(
    const float* __restrict__ gsum, float* __restrict__ ginfl)
{
    const int b = blockIdx.x;
    const int d = threadIdx.x;

    float s[KK];
    #pragma unroll
    for (int k = 0; k < KK; ++k) s[k] = -INFINITY;

    const float* mp = gsum + (size_t)b * NG * MSTR + d;
    float* ip = ginfl + (size_t)b * NG * KK * DD + d;
    float m0[NSUM], m1[NSUM];
    ld_map(mp, m0);
    #pragma unroll 1
    for (int g = 0; g + 2 < NG; g += 2) {
        ld_map(mp + MSTR, m1);
        #pragma unroll
        for (int k = 0; k < KK; ++k) ip[k * DD] = s[k];      // inflow BEFORE g
        apply_map(m0, s);
        ld_map(mp + 2 * MSTR, m0);
        #pragma unroll
        for (int k = 0; k < KK; ++k) ip[KK * DD + k * DD] = s[k];
        apply_map(m1, s);
        mp += 2 * MSTR;
        ip += 2 * KK * DD;
    }
    ld_map(mp + MSTR, m1);
    #pragma unroll
    for (int k = 0; k < KK; ++k) ip[k * DD] = s[k];
    apply_map(m0, s);
    #pragma unroll
    for (int k = 0; k < KK; ++k) ip[KK * DD + k * DD] = s[k];
    apply_map(m1, s);
}

// ---- pass 2c: one block per (b, group); replay G=16 chunk maps -> inflows ----
__global__ __launch_bounds__(256) void pass2c_chunk_inflows(
    const float* __restrict__ sum, const float* __restrict__ ginfl,
    float* __restrict__ infl)
{
    const int b = blockIdx.x / NG;
    const int g = blockIdx.x % NG;
    const int d = threadIdx.x;

    float s[KK];
    {
        const float* gp = ginfl + (size_t)blockIdx.x * KK * DD + d;  // region = b*NG+g
        #pragma unroll
        for (int k = 0; k < KK; ++k) s[k] = gp[k * DD];
    }

    const float* mp = sum + ((size_t)(b * C + g * G)) * MSTR + d;
    float* ip = infl + ((size_t)(b * C + g * G)) * KK * DD + d;
    float m0[NSUM], m1[NSUM];
    ld_map(mp, m0);
    #pragma unroll 1
    for (int ci = 0; ci + 2 < G; ci += 2) {
        ld_map(mp + MSTR, m1);
        #pragma unroll
        for (int k = 0; k < KK; ++k) ip[k * DD] = s[k];      // inflow BEFORE c
        apply_map(m0, s);
        ld_map(mp + 2 * MSTR, m0);
        #pragma unroll
        for (int k = 0; k < KK; ++k) ip[KK * DD + k * DD] = s[k];
        apply_map(m1, s);
        mp += 2 * MSTR;
        ip += 2 * KK * DD;
    }
    ld_map(mp + MSTR, m1);
    #pragma unroll
    for (int k = 0; k < KK; ++k) ip[k * DD] = s[k];
    apply_map(m0, s);
    #pragma unroll
    for (int k = 0; k < KK; ++k) ip[KK * DD + k * DD] = s[k];
    apply_map(m1, s);
}

// ---- pass 3: one block per (b, chunk); scan from inflow, emit outputs ----
__device__ __forceinline__ void step_scan(float x, const float (&wk)[KK],
                                          const float (&bk)[KK], float (&s)[KK])
{
    float g[KK];
    #pragma unroll
    for (int k = 0; k < KK; ++k) g[k] = fmaf(x, wk[k], bk[k]);
    #pragma unroll
    for (int k = KK - 1; k >= 1; --k) s[k] = fmaxf(s[k], s[k - 1] + g[k]);
    s[0] = fmaxf(s[0], g[0]);
}

__global__ __launch_bounds__(256) void pass3_scan(
    const float* __restrict__ X, const float* __restrict__ W,
    const float* __restrict__ Bv, const float* __restrict__ infl,
    float* __restrict__ out)
{
    constexpr int U = 16;               // L=32: two 16-row batches
    const int b = blockIdx.x / C;
    const int c = blockIdx.x % C;
    const int d = threadIdx.x;

    float wk[KK], bk[KK];
    #pragma unroll
    for (int k = 0; k < KK; ++k) { wk[k] = W[k * DD + d]; bk[k] = Bv[k * DD + d]; }

    float s[KK];
    {
        const float* ip = infl + (size_t)blockIdx.x * KK * DD + d;   // region = b*C+c
        #pragma unroll
        for (int k = 0; k < KK; ++k) s[k] = ip[k * DD];
    }

    const int t0 = c * L;
    const float* xp = X + ((size_t)(b * TT + t0)) * DD + d;
    // base indexed by cumulative in-chunk step t only (op never advances)
    float* op = out + (size_t)b * TOUT * DD + (ptrdiff_t)(t0 - (KK - 1)) * DD + d;

    float x0[U], x1[U];
    #pragma unroll
    for (int u = 0; u < U; ++u) x0[u] = xp[u * DD];
    #pragma unroll
    for (int u = 0; u < U; ++u) x1[u] = xp[(U + u) * DD];

    int t = 0;
    #pragma unroll
    for (int u = 0; u < U; ++u) {
        step_scan(x0[u], wk, bk, s);
        if (t0 + t >= KK - 1) __builtin_nontemporal_store(s[KK - 1], &op[t * DD]);
        ++t;
    }
    #pragma unroll
    for (int u = 0; u < U; ++u) {
        step_scan(x1[u], wk, bk, s);
        if (t0 + t >= KK - 1) __builtin_nontemporal_store(s[KK - 1], &op[t * DD]);
        ++t;
    }
}
} // namespace

extern "C" void kernel_launch(void* const* d_in, const int* in_sizes, int n_in,
                              void* d_out, int out_size, void* d_ws, size_t ws_size,
                              hipStream_t stream)
{
    const float* X  = (const float*)d_in[0];
    const float* W  = (const float*)d_in[1];
    const float* Bv = (const float*)d_in[2];
    float* out = (float*)d_out;

    // ws: sum 75.5 MB + gsum 4.7 MB + ginfl 1.05 MB + infl 16.8 MB = 98 MB
    float* sum   = (float*)d_ws;
    float* gsum  = sum   + (size_t)BB * C  * NSUM * DD;
    float* ginfl = gsum  + (size_t)BB * NG * NSUM * DD;
    float* infl  = ginfl + (size_t)BB * NG * KK   * DD;

    pass1_summaries<<<BB * C, 256, 0, stream>>>(X, W, Bv, sum);
    pass2a_groups<<<BB * NG, 256, 0, stream>>>(sum, gsum);
    pass2b_scan_groups<<<BB, 256, 0, stream>>>(gsum, ginfl);
    pass2c_chunk_inflows<<<BB * NG, 256, 0, stream>>>(sum, ginfl, infl);
    pass3_scan<<<BB * C, 256, 0, stream>>>(X, W, Bv, infl, out);
}